// Round 12
// baseline (133.068 us; speedup 1.0000x reference)
//
#include <hip/hip_runtime.h>
#include <math.h>

// Unfused mul/add EVERYWHERE (file scope): the exact-chain replication of
// numpy's einsum requires separately-rounded mul and add. Packed
// v_pk_mul_f32/v_pk_add_f32 are two independent IEEE-rounded ops per instr —
// allowed; fusion (fma) is not.
#pragma clang fp contract(off)

// MoE gate: logits = x @ W^T + bias ; softmax ; top-8 ; dense scatter.
// Outputs (float32): vals[16384*8] | idx[16384*8] | dense[16384*64].
//
// PASSED math (r3/r5/r6/r9/r10/r11) — DO NOT CHANGE (bit-exact np
// replication): np-einsum inner loop (npyv SSE2/SSE3, no FMA): 4 partial
// np-lanes (k mod 4), 16-element blocks ascending over the full K-walk,
// REVERSE vector order within block, every mul/add separately rounded, final
// SSE3 hadd tree (L0+L1)+(L2+L3). Top-8 ranked by these exact f32 logits,
// strict >, lowest index on tie; softmax = exp(l-max), np pairwise-8 sum,
// IEEE div.
//
// r12: r11 kept ~148us despite 30% less LDS traffic -> not LDS-throughput
// bound; suspect per-tile HBM-latency stall (prefetch distance 1: vmcnt(6)
// waits on loads issued only ~600cy earlier; HBM ~900cy; 8 waves/CU can't
// hide it). Change: NBUF=4, prefetch distance 2, vmcnt(12) steady-state
// (awaited loads issued ~2 iterations = ~1200cy earlier). Tail peeled with
// vmcnt(6)/vmcnt(0). Max concurrent span stage(kt+3) vs compute(kt) =
// buffer distance 3 mod 4 -> race-free. LDS 72KB -> still 2 blocks/CU.

#define NROWS 16384
#define DIM   2048
#define NE    64
#define DC    32
#define NTILES (DIM / DC)   // 64
#define TROWS 128
#define NBUF  4

typedef float vf2 __attribute__((ext_vector_type(2)));
typedef float vf4 __attribute__((ext_vector_type(4)));

__device__ __forceinline__ void ld16_lds(const float* g, void* l) {
  __builtin_amdgcn_global_load_lds((const __attribute__((address_space(1))) void*)g,
                                   (__attribute__((address_space(3))) void*)l, 16, 0, 0);
}
__device__ __forceinline__ void ld4_lds(const float* g, void* l) {
  __builtin_amdgcn_global_load_lds((const __attribute__((address_space(1))) void*)g,
                                   (__attribute__((address_space(3))) void*)l, 4, 0, 0);
}

__global__ __launch_bounds__(256, 2)
void logits_kernel(const float* __restrict__ x, const float* __restrict__ w,
                   const float* __restrict__ bias, float* __restrict__ lg)
{
  __shared__ vf4 xs[NBUF][TROWS * (DC / 4)];   // 4 x 16 KB
  __shared__ vf4 ws[NBUF][16 * (DC / 4)];      // 4 x 2 KB

  const int t    = threadIdx.x;
  const int wv   = t >> 6;      // 0..3 -> expert quad within group
  const int lane = t & 63;
  // XCD decode: 4 sibling blocks (same 128 rows, expert groups 0..3) share an
  // XCD so the x-tile is fetched once per XCD L2 (default assignment = bid&7).
  const int bid = blockIdx.x;          // 0..511
  const int ix  = bid >> 3;            // 0..63
  const int qg  = ix & 3;              // expert group (16 experts)
  const int rg  = (bid & 7) + ((ix >> 2) << 3);  // row group 0..127 (bijective)
  const int rowBase = rg << 7;         // 128 rows per block
  const int e_base  = __builtin_amdgcn_readfirstlane((qg << 4) | (wv << 2));

  auto stage = [&](int buf, int kt) {
    const int d0 = kt * DC;
#pragma unroll
    for (int it = 0; it < 4; ++it) {
      int q   = (it << 8) + t;     // vf4 index in [128][8] x-tile
      int row = q >> 3;
      int sp  = q & 7;
      int ss  = sp ^ (row & 7);    // swizzle on the GLOBAL source (involution)
      const float* g = x + (size_t)(rowBase + row) * DIM + d0 + (ss << 2);
      ld16_lds(g, &xs[buf][q]);
    }
    // W tile: 16 experts x 32 floats = 512 dwords; 2 uniform size-4 loads per
    // thread, lane-ordered so each wave instr writes 256 contiguous LDS bytes.
#pragma unroll
    for (int j = 0; j < 2; ++j) {
      int m = (wv << 7) + (j << 6) + lane;   // dword idx 0..511
      int e = m >> 5, c = m & 31;
      const float* g = w + (size_t)(qg * 16 + e) * DIM + d0 + c;
      ld4_lds(g, (float*)&ws[buf][0] + m);
    }
  };

  // acc01[r][e] = np-lanes (L0,L1); acc23[r][e] = (L2,L3); r = row slot.
  vf2 acc01[2][4], acc23[2][4];
#pragma unroll
  for (int r = 0; r < 2; ++r)
#pragma unroll
    for (int e = 0; e < 4; ++e) { acc01[r][e] = (vf2)(0.f); acc23[r][e] = (vf2)(0.f); }

  auto compute = [&](int buf) {
    const int sw = lane & 7;     // (lane+64)&7 == lane&7: same swizzle both rows
#pragma unroll
    for (int b = 0; b < 2; ++b) {        // np 16-blocks, ascending
      vf4 q0[2], q1[2], q2[2], q3[2];
#pragma unroll
      for (int r = 0; r < 2; ++r) {
        const vf4* xr = &xs[buf][(lane + (r << 6)) << 3];
        q0[r] = xr[(4 * b + 0) ^ sw];
        q1[r] = xr[(4 * b + 1) ^ sw];
        q2[r] = xr[(4 * b + 2) ^ sw];
        q3[r] = xr[(4 * b + 3) ^ sw];
      }
#pragma unroll
      for (int e = 0; e < 4; ++e) {
        const vf4* we = &ws[buf][(((wv << 2) + e) << 3) + (b << 2)];  // uniform -> broadcast
        vf4 r0 = we[0], r1 = we[1], r2 = we[2], r3 = we[3];
#pragma unroll
        for (int r = 0; r < 2; ++r) {
          // np chain, reverse vector order (j=3,2,1,0), mul/add separately
          // rounded; .xy -> acc01, .zw -> acc23. Chains per (r,e) independent.
          acc01[r][e] = acc01[r][e] + q3[r].xy * r3.xy;
          acc23[r][e] = acc23[r][e] + q3[r].zw * r3.zw;
          acc01[r][e] = acc01[r][e] + q2[r].xy * r2.xy;
          acc23[r][e] = acc23[r][e] + q2[r].zw * r2.zw;
          acc01[r][e] = acc01[r][e] + q1[r].xy * r1.xy;
          acc23[r][e] = acc23[r][e] + q1[r].zw * r1.zw;
          acc01[r][e] = acc01[r][e] + q0[r].xy * r0.xy;
          acc23[r][e] = acc23[r][e] + q0[r].zw * r0.zw;
        }
      }
    }
  };

  // ---- 4-buffer, prefetch distance 2, ONE barrier per tile ----
  stage(0, 0);
  stage(1, 1);
#pragma unroll 1
  for (int kt = 0; kt < NTILES - 2; ++kt) {
    stage((kt + 2) & 3, kt + 2);                       // 6 loads -> buf (kt+2)%4
    // stage(kt) landed iff <=12 outstanding (stage(kt+1) 6 + stage(kt+2) 6).
    asm volatile("s_waitcnt vmcnt(12)" ::: "memory");
    __builtin_amdgcn_s_barrier();
    compute(kt & 3);
  }
  // kt = NTILES-2: outstanding = stage(NTILES-2) + stage(NTILES-1); wait to 6.
  asm volatile("s_waitcnt vmcnt(6)" ::: "memory");
  __builtin_amdgcn_s_barrier();
  compute((NTILES - 2) & 3);
  // kt = NTILES-1: drain.
  asm volatile("s_waitcnt vmcnt(0)" ::: "memory");
  __builtin_amdgcn_s_barrier();
  compute((NTILES - 1) & 3);

  {
    // SSE3 hadd tree per (row, expert): (L0+L1)+(L2+L3), then +bias (zeros).
#pragma unroll
    for (int r = 0; r < 2; ++r) {
      float4 res;
      float s01, s23;
      s01 = acc01[r][0].x + acc01[r][0].y; s23 = acc23[r][0].x + acc23[r][0].y;
      res.x = (s01 + s23) + bias[e_base + 0];
      s01 = acc01[r][1].x + acc01[r][1].y; s23 = acc23[r][1].x + acc23[r][1].y;
      res.y = (s01 + s23) + bias[e_base + 1];
      s01 = acc01[r][2].x + acc01[r][2].y; s23 = acc23[r][2].x + acc23[r][2].y;
      res.z = (s01 + s23) + bias[e_base + 2];
      s01 = acc01[r][3].x + acc01[r][3].y; s23 = acc23[r][3].x + acc23[r][3].y;
      res.w = (s01 + s23) + bias[e_base + 3];
      *(float4*)(lg + (size_t)(rowBase + lane + (r << 6)) * NE + e_base) = res;
    }
  }
}

// B: per-row softmax + top-8 + dense scatter, logits read+overwritten in place.
__global__ __launch_bounds__(256, 1)
void finish_kernel(float* __restrict__ gate, float* __restrict__ out_vals,
                   float* __restrict__ out_idx)
{
  const int r = blockIdx.x * 256 + threadIdx.x;
  float l[NE], p[NE];
  {
    const float4* gp = (const float4*)(gate + (size_t)r * NE);
    float4* lp = (float4*)l;
#pragma unroll
    for (int i = 0; i < 16; ++i) lp[i] = gp[i];
  }
  float m = l[0];
#pragma unroll
  for (int e = 1; e < NE; ++e) m = fmaxf(m, l[e]);
#pragma unroll
  for (int e = 0; e < NE; ++e) p[e] = expf(l[e] - m);
  float rs[8];
#pragma unroll
  for (int j = 0; j < 8; ++j) rs[j] = p[j];
#pragma unroll
  for (int i = 8; i < NE; i += 8)
#pragma unroll
    for (int j = 0; j < 8; ++j) rs[j] = rs[j] + p[i + j];
  float s = ((rs[0] + rs[1]) + (rs[2] + rs[3])) + ((rs[4] + rs[5]) + (rs[6] + rs[7]));
#pragma unroll
  for (int e = 0; e < NE; ++e) p[e] = p[e] / s;

  // top-8 ranked by exact logits (r3-passed semantics): strict >, low idx tie.
  unsigned long long used = 0;
#pragma unroll
  for (int k = 0; k < 8; ++k) {
    float best = -INFINITY; int bi = 0;
#pragma unroll
    for (int e = 0; e < NE; ++e) {
      bool ok = (((used >> e) & 1ull) == 0ull) && (l[e] > best);
      best = ok ? l[e] : best;
      bi   = ok ? e    : bi;
    }
    used |= 1ull << bi;
    out_vals[(size_t)r * 8 + k] = p[bi];
    out_idx [(size_t)r * 8 + k] = (float)bi;
  }

  {
    float4* gp = (float4*)(gate + (size_t)r * NE);
#pragma unroll
    for (int i = 0; i < 16; ++i) {
      int e = i << 2;
      float4 v;
      v.x = ((used >> (e + 0)) & 1ull) ? p[e + 0] : 0.0f;
      v.y = ((used >> (e + 1)) & 1ull) ? p[e + 1] : 0.0f;
      v.z = ((used >> (e + 2)) & 1ull) ? p[e + 2] : 0.0f;
      v.w = ((used >> (e + 3)) & 1ull) ? p[e + 3] : 0.0f;
      gp[i] = v;
    }
  }
}

extern "C" void kernel_launch(void* const* d_in, const int* in_sizes, int n_in,
                              void* d_out, int out_size, void* d_ws, size_t ws_size,
                              hipStream_t stream) {
  const float* x    = (const float*)d_in[0];
  const float* w    = (const float*)d_in[1];
  const float* bias = (const float*)d_in[2];
  float* out   = (float*)d_out;
  float* vals  = out;                       // 16384*8
  float* idx   = out + (size_t)NROWS * 8;   // 16384*8
  float* dense = out + (size_t)NROWS * 16;  // 16384*64 (A's logit scratch)
  (void)in_sizes; (void)n_in; (void)out_size; (void)d_ws; (void)ws_size;
  logits_kernel<<<dim3(512), dim3(256), 0, stream>>>(x, w, bias, dense);
  finish_kernel<<<dim3(NROWS / 256), dim3(256), 0, stream>>>(dense, vals, idx);
}

// Round 13
// 115.447 us; speedup vs baseline: 1.1526x; 1.1526x over previous
//
#include <hip/hip_runtime.h>
#include <math.h>

// Unfused mul/add everywhere: the np-exact chain (phase 3) requires separately
// rounded mul/add; phases 1-2 are unaffected semantically.
#pragma clang fp contract(off)

// MoE gate: logits = x @ W^T + bias ; softmax ; top-8 ; dense scatter.
// Outputs (float32): vals[16384*8] | idx[16384*8] | dense[16384*64].
//
// r13 architecture (escape the LDS-pipe roofline of the SIMT-f32 family):
//  P1 mfma_logits: split-bf16 (x=xh+xl, w=wh+wl) 3-pass MFMA GEMM -> approx
//     logits (|err| ~2.5e-5) into the dense scratch region.
//  P2 finish: np-style softmax/top-8 from approx logits (probs tolerance
//     ~1e-3 >> 2.5e-5). Rows with any adjacent top-9 gap < MARGIN=1e-4 are
//     flagged (~50/16384 expected) with <=12 candidates into d_ws.
//     Non-flagged rows provably have np-identical top-8 set AND order.
//  P3 exact_fix: per flagged row, bit-exact np chain (npyv SSE2/SSE3: 4
//     partial lanes k mod 4, 16-blocks ascending, REVERSE in-block order,
//     unfused, hadd tree (L0+L1)+(L2+L3)) for the candidates; re-rank
//     strict-> lowest-index-tie; rewrite vals/idx/dense for that row.

#define NROWS 16384
#define DIM   2048
#define NE    64
#define KSTEP 32
#define NKT   (DIM / KSTEP)   // 64
#define MARGIN 1e-4f
#define MAXCAND 12

typedef float f32x4 __attribute__((ext_vector_type(4)));
typedef short s16x8 __attribute__((ext_vector_type(8)));

__device__ __forceinline__ void ld16_lds(const float* g, void* l) {
  __builtin_amdgcn_global_load_lds((const __attribute__((address_space(1))) void*)g,
                                   (__attribute__((address_space(3))) void*)l, 16, 0, 0);
}
__device__ __forceinline__ unsigned short bf16_rne(float f) {
  unsigned u = __builtin_bit_cast(unsigned, f);
  u += 0x7FFFu + ((u >> 16) & 1u);
  return (unsigned short)(u >> 16);
}
__device__ __forceinline__ float bf16f(unsigned short h) {
  return __builtin_bit_cast(float, (unsigned)h << 16);
}
__device__ __forceinline__ void cvt8(const f32x4 a, const f32x4 b, s16x8* hi, s16x8* lo) {
#pragma unroll
  for (int j = 0; j < 4; ++j) {
    unsigned short h = bf16_rne(a[j]);
    (*hi)[j] = (short)h; (*lo)[j] = (short)bf16_rne(a[j] - bf16f(h));
  }
#pragma unroll
  for (int j = 0; j < 4; ++j) {
    unsigned short h = bf16_rne(b[j]);
    (*hi)[4 + j] = (short)h; (*lo)[4 + j] = (short)bf16_rne(b[j] - bf16f(h));
  }
}

// ---------------- Phase 1: split-bf16 MFMA logits ----------------
// Grid 512 x 128thr (2 waves). Block: 32 rows x all 64 experts.
// Frag layout (16x16x32 bf16): A lane l -> row l&15, k=(l>>4)*8+j;
// B lane l -> col l&15, k=(l>>4)*8+j; D: col=lane&15, row=(lane>>4)*4+reg.
// Converter thread t writes frags in exact lane order -> linear conflict-free
// b128 LDS on both sides.
__global__ __launch_bounds__(128, 1)
void mfma_logits(const float* __restrict__ x, const float* __restrict__ w,
                 const float* __restrict__ bias, float* __restrict__ lg)
{
  __shared__ s16x8 Ah[2][64], Al[2][64], Bh[4][64], Bl[4][64];  // 12 KB

  const int t = threadIdx.x;
  const int wv = t >> 6, lane = t & 63;
  const int rowBase = blockIdx.x << 5;

  // x loader: thread t -> row t>>2 (0..31), k-chunk (t&3)*8
  const int xr = t >> 2;
  const int xm = xr >> 4;
  const int xl = ((t & 3) << 4) | (xr & 15);
  const float* xbase = x + (size_t)(rowBase + xr) * DIM + ((t & 3) << 3);

  // W loader: thread t -> expert t>>1 (0..63), k-chunks 2(t&1), 2(t&1)+1
  const int we = t >> 1;
  const int wn = we >> 4;
  const int kg0 = (t & 1) << 1;
  const int wl0 = (kg0 << 4) | (we & 15);
  const int wl1 = ((kg0 + 1) << 4) | (we & 15);
  const float* wbase = w + (size_t)we * DIM + ((t & 1) << 4);

  f32x4 acc[4];
#pragma unroll
  for (int n = 0; n < 4; ++n) acc[n] = (f32x4)(0.f);

  // prologue: f32 regs for k-tile 0
  f32x4 cx0 = *(const f32x4*)(xbase);
  f32x4 cx1 = *(const f32x4*)(xbase + 4);
  f32x4 cw0 = *(const f32x4*)(wbase);
  f32x4 cw1 = *(const f32x4*)(wbase + 4);
  f32x4 cw2 = *(const f32x4*)(wbase + 8);
  f32x4 cw3 = *(const f32x4*)(wbase + 12);

#pragma unroll 1
  for (int kt = 0; kt < NKT; ++kt) {
    const int kn = ((kt + 1) & (NKT - 1)) * KSTEP;   // wraps harmlessly at end
    f32x4 nx0 = *(const f32x4*)(xbase + kn);
    f32x4 nx1 = *(const f32x4*)(xbase + kn + 4);
    f32x4 nw0 = *(const f32x4*)(wbase + kn);
    f32x4 nw1 = *(const f32x4*)(wbase + kn + 4);
    f32x4 nw2 = *(const f32x4*)(wbase + kn + 8);
    f32x4 nw3 = *(const f32x4*)(wbase + kn + 12);

    // convert current f32 regs -> bf16 hi/lo frags in LDS
    {
      s16x8 hi, lo;
      cvt8(cx0, cx1, &hi, &lo);
      Ah[xm][xl] = hi; Al[xm][xl] = lo;
      cvt8(cw0, cw1, &hi, &lo);
      Bh[wn][wl0] = hi; Bl[wn][wl0] = lo;
      cvt8(cw2, cw3, &hi, &lo);
      Bh[wn][wl1] = hi; Bl[wn][wl1] = lo;
    }
    asm volatile("s_waitcnt lgkmcnt(0)" ::: "memory");
    __builtin_amdgcn_s_barrier();      // frags visible (vmcnt untouched)

    {
      s16x8 a_h = Ah[wv][lane];
      s16x8 a_l = Al[wv][lane];
#pragma unroll
      for (int n = 0; n < 4; ++n) {
        s16x8 b_h = Bh[n][lane];
        s16x8 b_l = Bl[n][lane];
        acc[n] = __builtin_amdgcn_mfma_f32_16x16x32_bf16(a_l, b_h, acc[n], 0, 0, 0);
        acc[n] = __builtin_amdgcn_mfma_f32_16x16x32_bf16(a_h, b_l, acc[n], 0, 0, 0);
        acc[n] = __builtin_amdgcn_mfma_f32_16x16x32_bf16(a_h, b_h, acc[n], 0, 0, 0);
      }
    }
    __builtin_amdgcn_s_barrier();      // all reads done before next writes

    cx0 = nx0; cx1 = nx1; cw0 = nw0; cw1 = nw1; cw2 = nw2; cw3 = nw3;
  }

  // epilogue: D col=lane&15, row=(lane>>4)*4+reg
  const int orow = rowBase + (wv << 4) + ((lane >> 4) << 2);
  const int ocol = lane & 15;
#pragma unroll
  for (int n = 0; n < 4; ++n)
#pragma unroll
    for (int r = 0; r < 4; ++r)
      lg[(size_t)(orow + r) * NE + (n << 4) + ocol] = acc[n][r] + bias[(n << 4) + ocol];
}

// ---------------- Phase 2: finish (softmax/top-8/dense/flag) ----------------
__global__ __launch_bounds__(256, 1)
void finish_kernel(float* __restrict__ gate, float* __restrict__ out_vals,
                   float* __restrict__ out_idx, int* __restrict__ flags, int maxf)
{
  const int r = blockIdx.x * 256 + threadIdx.x;
  float l[NE], p[NE];
  {
    const float4* gp = (const float4*)(gate + (size_t)r * NE);
    float4* lp = (float4*)l;
#pragma unroll
    for (int i = 0; i < 16; ++i) lp[i] = gp[i];
  }
  float m = l[0];
#pragma unroll
  for (int e = 1; e < NE; ++e) m = fmaxf(m, l[e]);
#pragma unroll
  for (int e = 0; e < NE; ++e) p[e] = expf(l[e] - m);
  float rs[8];
#pragma unroll
  for (int j = 0; j < 8; ++j) rs[j] = p[j];
#pragma unroll
  for (int i = 8; i < NE; i += 8)
#pragma unroll
    for (int j = 0; j < 8; ++j) rs[j] = rs[j] + p[i + j];
  float s = ((rs[0] + rs[1]) + (rs[2] + rs[3])) + ((rs[4] + rs[5]) + (rs[6] + rs[7]));
#pragma unroll
  for (int e = 0; e < NE; ++e) p[e] = p[e] / s;

  // top-9 scan (ranked by logits, strict >, lowest index on tie)
  unsigned long long used = 0, used8 = 0;
  float sval[9]; int sidx[9];
#pragma unroll
  for (int k = 0; k < 9; ++k) {
    float best = -INFINITY; int bi = 0;
#pragma unroll
    for (int e = 0; e < NE; ++e) {
      bool ok = (((used >> e) & 1ull) == 0ull) && (l[e] > best);
      best = ok ? l[e] : best;
      bi   = ok ? e    : bi;
    }
    used |= 1ull << bi;
    sval[k] = best; sidx[k] = bi;
    if (k == 7) used8 = used;
  }
#pragma unroll
  for (int k = 0; k < 8; ++k) {
    out_vals[(size_t)r * 8 + k] = p[sidx[k]];
    out_idx [(size_t)r * 8 + k] = (float)sidx[k];
  }
  {
    float4* gp = (float4*)(gate + (size_t)r * NE);
#pragma unroll
    for (int i = 0; i < 16; ++i) {
      int e = i << 2;
      float4 v;
      v.x = ((used8 >> (e + 0)) & 1ull) ? p[e + 0] : 0.0f;
      v.y = ((used8 >> (e + 1)) & 1ull) ? p[e + 1] : 0.0f;
      v.z = ((used8 >> (e + 2)) & 1ull) ? p[e + 2] : 0.0f;
      v.w = ((used8 >> (e + 3)) & 1ull) ? p[e + 3] : 0.0f;
      gp[i] = v;
    }
  }
  // flag near-tie rows
  float ming = INFINITY;
#pragma unroll
  for (int k = 1; k < 9; ++k) ming = fminf(ming, sval[k - 1] - sval[k]);
  if (ming < MARGIN && maxf > 0) {
    int cand[MAXCAND]; float cp[MAXCAND]; int n = 0; bool ovf = false;
    const float thr = sval[7] - MARGIN;
    for (int e = 0; e < NE; ++e) {
      if (l[e] >= thr) {
        if (n < MAXCAND) { cand[n] = e; cp[n] = p[e]; ++n; }
        else ovf = true;
      }
    }
    if (!ovf) {   // overflow (>12 within margin) is ~1e-9/row: keep approx result
      int slot = atomicAdd(flags, 1);
      if (slot < maxf) {
        int* rec = flags + 4 + slot * 32;
        rec[0] = r; rec[1] = n;
#pragma unroll
        for (int i = 0; i < MAXCAND; ++i) rec[2 + i] = (i < n) ? cand[i] : 0;
        float* fp = (float*)(rec + 14);
#pragma unroll
        for (int i = 0; i < MAXCAND; ++i) fp[i] = (i < n) ? cp[i] : 0.f;
      }
    }
  }
}

// ---------------- Phase 3: np-exact fixup for flagged rows ----------------
__global__ __launch_bounds__(64, 1)
void exact_fix(const float* __restrict__ x, const float* __restrict__ w,
               const float* __restrict__ bias, const int* __restrict__ flags,
               int maxf, float* __restrict__ out_vals, float* __restrict__ out_idx,
               float* __restrict__ gate)
{
  __shared__ float xs_[DIM];                 // 8 KB
  __shared__ float wl_[MAXCAND * DIM];       // 96 KB
  __shared__ float exl[MAXCAND];

  int count = flags[0]; if (count > maxf) count = maxf;
  const int lane = threadIdx.x;

  for (int recI = blockIdx.x; recI < count; recI += (int)gridDim.x) {
    const int* rec = flags + 4 + recI * 32;
    const int row = rec[0], n = rec[1];

    // stage x row + candidate W rows (linear LDS dest = base + lane*16)
#pragma unroll
    for (int i = 0; i < 8; ++i)
      ld16_lds(x + (size_t)row * DIM + i * 256 + lane * 4, &xs_[i * 256 + lane * 4]);
    for (int c = 0; c < n; ++c)
#pragma unroll
      for (int i = 0; i < 8; ++i)
        ld16_lds(w + (size_t)rec[2 + c] * DIM + i * 256 + lane * 4,
                 &wl_[c * DIM + i * 256 + lane * 4]);
    asm volatile("s_waitcnt vmcnt(0)" ::: "memory");
    __builtin_amdgcn_s_barrier();

    // np-exact chain: lane = cand*4 + npLane j; reverse in-block, unfused
    const int c = lane >> 2, jj = lane & 3;
    const int cw = (c < n) ? c : 0;
    const float* wrow = &wl_[cw * DIM];
    float a = 0.f;
#pragma unroll 4
    for (int b = 0; b < 128; ++b) {
      const int k = (b << 4) + jj;
      a = a + xs_[k + 12] * wrow[k + 12];
      a = a + xs_[k + 8]  * wrow[k + 8];
      a = a + xs_[k + 4]  * wrow[k + 4];
      a = a + xs_[k]      * wrow[k];
    }
    // SSE3 hadd tree: (L0+L1)+(L2+L3)  (f32 add is commutative-exact)
    float o1 = __shfl_xor(a, 1);
    float s01 = a + o1;
    float o2 = __shfl_xor(s01, 2);
    float tot = (s01 + o2) + bias[rec[2 + cw]];
    if (jj == 0 && c < n) exl[c] = tot;
    __syncthreads();

    if (lane == 0) {
      unsigned used = 0;
      const float* cp = (const float*)(rec + 14);
      for (int k = 0; k < 8; ++k) {
        float best = -INFINITY; int bi = 0;
        for (int c2 = 0; c2 < n; ++c2) {
          bool ok = (((used >> c2) & 1u) == 0u) && (exl[c2] > best);
          best = ok ? exl[c2] : best;
          bi   = ok ? c2      : bi;
        }
        used |= 1u << bi;
        out_vals[(size_t)row * 8 + k] = cp[bi];
        out_idx [(size_t)row * 8 + k] = (float)rec[2 + bi];
      }
      for (int c2 = 0; c2 < n; ++c2)
        gate[(size_t)row * NE + rec[2 + c2]] = ((used >> c2) & 1u) ? cp[c2] : 0.f;
    }
    __syncthreads();
  }
}

extern "C" void kernel_launch(void* const* d_in, const int* in_sizes, int n_in,
                              void* d_out, int out_size, void* d_ws, size_t ws_size,
                              hipStream_t stream) {
  const float* x    = (const float*)d_in[0];
  const float* w    = (const float*)d_in[1];
  const float* bias = (const float*)d_in[2];
  float* out   = (float*)d_out;
  float* vals  = out;                       // 16384*8
  float* idx   = out + (size_t)NROWS * 8;   // 16384*8
  float* dense = out + (size_t)NROWS * 16;  // 16384*64 (P1 logit scratch)
  (void)in_sizes; (void)n_in; (void)out_size;

  int maxf = 0;
  if (ws_size >= 16 + 32 * 4) {
    size_t cap = (ws_size / 4 - 4) / 32;
    maxf = (int)(cap > 2048 ? 2048 : cap);
  }
  int* flags = (int*)d_ws;

  mfma_logits<<<dim3(NROWS / 32), dim3(128), 0, stream>>>(x, w, bias, dense);
  if (maxf > 0) hipMemsetAsync(d_ws, 0, 16, stream);
  finish_kernel<<<dim3(NROWS / 256), dim3(256), 0, stream>>>(dense, vals, idx, flags, maxf);
  if (maxf > 0)
    exact_fix<<<dim3(128), dim3(64), 0, stream>>>(x, w, bias, flags, maxf, vals, idx, dense);
}